// Round 8
// baseline (263.921 us; speedup 1.0000x reference)
//
#include <hip/hip_runtime.h>
#include <math.h>

#define TN 2048            // T
#define NF 4096            // Bluestein FFT length
#define NB 64              // batch
#define LF 6142LL          // L = 3T-2
#define L2F 12284LL        // 2L
#define PI_D 3.14159265358979323846264338327950288
#define C8 0.70710678118654752440084436210485

typedef double2 cpx;

__device__ __forceinline__ cpx cmk(double a, double b){ cpx r; r.x=a; r.y=b; return r; }
__device__ __forceinline__ cpx cadd(cpx a, cpx b){ return cmk(a.x+b.x, a.y+b.y); }
__device__ __forceinline__ cpx csub(cpx a, cpx b){ return cmk(a.x-b.x, a.y-b.y); }
__device__ __forceinline__ cpx cmul(cpx a, cpx b){ return cmk(a.x*b.x - a.y*b.y, a.x*b.y + a.y*b.x); }
__device__ __forceinline__ cpx cmulc(cpx a, cpx b){ return cmk(a.x*b.x + a.y*b.y, a.y*b.x - a.x*b.y); } // a*conj(b)

// LDS swizzle (cpx granularity, involution)
__device__ __forceinline__ int SW(int i){ return i ^ ((i >> 3) & 7); }

// wave-local sync: fences compiler + drains lgkmcnt; no cross-wave lock-step
__device__ __forceinline__ void wsync(){
  __builtin_amdgcn_wave_barrier();
  asm volatile("s_waitcnt lgkmcnt(0)" ::: "memory");
  __builtin_amdgcn_wave_barrier();
}

// ---------- 8-point register FFT (DIF, natural in; reg q holds freq R8[q]={0,4,2,6,1,5,3,7})
__device__ __forceinline__ void fft8_bc(cpx* a){
  cpx u, v, d;
  u=a[0]; v=a[2]; a[0]=cadd(u,v); a[2]=csub(u,v);
  u=a[1]; v=a[3]; a[1]=cadd(u,v); d=csub(u,v); a[3]=cmk(d.y, -d.x);
  u=a[4]; v=a[6]; a[4]=cadd(u,v); a[6]=csub(u,v);
  u=a[5]; v=a[7]; a[5]=cadd(u,v); d=csub(u,v); a[7]=cmk(d.y, -d.x);
  u=a[0]; v=a[1]; a[0]=cadd(u,v); a[1]=csub(u,v);
  u=a[2]; v=a[3]; a[2]=cadd(u,v); a[3]=csub(u,v);
  u=a[4]; v=a[5]; a[4]=cadd(u,v); a[5]=csub(u,v);
  u=a[6]; v=a[7]; a[6]=cadd(u,v); a[7]=csub(u,v);
}
__device__ __forceinline__ void fft8(cpx* a){
  cpx u, v, d;
  u=a[0]; v=a[4]; a[0]=cadd(u,v); a[4]=csub(u,v);
  u=a[1]; v=a[5]; a[1]=cadd(u,v); d=csub(u,v); a[5]=cmk(C8*(d.x+d.y), C8*(d.y-d.x));
  u=a[2]; v=a[6]; a[2]=cadd(u,v); d=csub(u,v); a[6]=cmk(d.y, -d.x);
  u=a[3]; v=a[7]; a[3]=cadd(u,v); d=csub(u,v); a[7]=cmk(C8*(d.y-d.x), -C8*(d.x+d.y));
  fft8_bc(a);
}
// unscaled inverse (input in fft8 reg order, output natural, x8)
__device__ __forceinline__ void ifft8(cpx* a){
  cpx u, v, t;
  u=a[0]; v=a[1]; a[0]=cadd(u,v); a[1]=csub(u,v);
  u=a[2]; v=a[3]; a[2]=cadd(u,v); a[3]=csub(u,v);
  u=a[4]; v=a[5]; a[4]=cadd(u,v); a[5]=csub(u,v);
  u=a[6]; v=a[7]; a[6]=cadd(u,v); a[7]=csub(u,v);
  u=a[0]; v=a[2]; a[0]=cadd(u,v); a[2]=csub(u,v);
  u=a[1]; t=a[3]; v=cmk(-t.y, t.x); a[1]=cadd(u,v); a[3]=csub(u,v);
  u=a[4]; v=a[6]; a[4]=cadd(u,v); a[6]=csub(u,v);
  u=a[5]; t=a[7]; v=cmk(-t.y, t.x); a[5]=cadd(u,v); a[7]=csub(u,v);
  u=a[0]; v=a[4]; a[0]=cadd(u,v); a[4]=csub(u,v);
  u=a[1]; t=a[5]; v=cmk(C8*(t.x-t.y), C8*(t.x+t.y)); a[1]=cadd(u,v); a[5]=csub(u,v);
  u=a[2]; t=a[6]; v=cmk(-t.y, t.x); a[2]=cadd(u,v); a[6]=csub(u,v);
  u=a[3]; t=a[7]; v=cmk(-C8*(t.x+t.y), C8*(t.x-t.y)); a[3]=cadd(u,v); a[7]=csub(u,v);
}
// pruned inverse: only outputs a[0..3] valid (skip the 4 csubs of the last level)
__device__ __forceinline__ void ifft8h(cpx* a){
  cpx u, v, t;
  u=a[0]; v=a[1]; a[0]=cadd(u,v); a[1]=csub(u,v);
  u=a[2]; v=a[3]; a[2]=cadd(u,v); a[3]=csub(u,v);
  u=a[4]; v=a[5]; a[4]=cadd(u,v); a[5]=csub(u,v);
  u=a[6]; v=a[7]; a[6]=cadd(u,v); a[7]=csub(u,v);
  u=a[0]; v=a[2]; a[0]=cadd(u,v); a[2]=csub(u,v);
  u=a[1]; t=a[3]; v=cmk(-t.y, t.x); a[1]=cadd(u,v); a[3]=csub(u,v);
  u=a[4]; v=a[6]; a[4]=cadd(u,v); a[6]=csub(u,v);
  u=a[5]; t=a[7]; v=cmk(-t.y, t.x); a[5]=cadd(u,v); a[7]=csub(u,v);
  u=a[0]; v=a[4]; a[0]=cadd(u,v);
  u=a[1]; t=a[5]; v=cmk(C8*(t.x-t.y), C8*(t.x+t.y)); a[1]=cadd(u,v);
  u=a[2]; t=a[6]; v=cmk(-t.y, t.x); a[2]=cadd(u,v);
  u=a[3]; t=a[7]; v=cmk(-C8*(t.x+t.y), C8*(t.x-t.y)); a[3]=cadd(u,v);
}
// 4-point DIF; reg q holds freq R4[q] = {0,2,1,3}
__device__ __forceinline__ void fft4(cpx* a){
  cpx u, v, d;
  u=a[0]; v=a[2]; a[0]=cadd(u,v); a[2]=csub(u,v);
  u=a[1]; v=a[3]; a[1]=cadd(u,v); d=csub(u,v); a[3]=cmk(d.y, -d.x);
  u=a[0]; v=a[1]; a[0]=cadd(u,v); a[1]=csub(u,v);
  u=a[2]; v=a[3]; a[2]=cadd(u,v); a[3]=csub(u,v);
}

// generic radix-8 DIF stage for 256-thread blocks (used by chat builder)
template<int LM, int NBF>
__device__ __forceinline__ void r8_stage_fwd(cpx* buf, const cpx* tw){
  const int R[8] = {0,4,2,6,1,5,3,7};
  for (int b = threadIdx.x; b < NBF; b += 256){
    int pos = b & ((1 << LM) - 1);
    int base = ((b >> LM) << (LM + 3)) | pos;
    cpx a[8];
    #pragma unroll
    for (int j = 0; j < 8; j++) a[j] = buf[SW(base + (j << LM))];
    fft8(a);
    #pragma unroll
    for (int q = 0; q < 8; q++){
      int k = R[q];
      cpx v = a[q];
      if (k) v = cmul(v, tw[(pos * k) << (9 - LM)]);
      buf[SW(base + (k << LM))] = v;
    }
  }
}

// ---------- K1: filters + tables
__global__ __launch_bounds__(256) void k_prep(
    const float* fw1, const float* fb1, const float* fw2, const float* fb2,
    const float* gw1, const float* gb1, const float* gw2, const float* gb2,
    const float* pw1, const float* pb1, const float* pw2, const float* pb2,
    const float* qw1, const float* qb1, const float* qw2, const float* qb2,
    double* arr, cpx* tw, cpx* Q, cpx* g2)
{
  int gid = blockIdx.x * 256 + threadIdx.x;   // < 8192
  if (gid < 4096){
    double s, c;
    sincos(-2.0 * PI_D * (double)gid / 4096.0, &s, &c);
    tw[gid] = cmk(c, s);
  }
  if (gid < 2048){
    long long i = gid;
    double s, c;
    long long a = ((2LL * TN - 2) * i) % LF;
    long long b = (i * i) % L2F;
    long long comb = (2 * a + b) % L2F;
    sincos(PI_D * (double)comb / (double)LF, &s, &c);
    Q[gid] = cmk(c, s);
    long long a2 = ((2LL * TN - 2 + i) * (TN - 1)) % LF;
    long long comb2 = (2 * a2 + b) % L2F;
    double phi = PI_D * (double)comb2 / (double)LF;
    double scale = 1.0 / ((double)LF * (double)LF) / (4096.0 * 4096.0);
    sincos(2.0 * phi, &s, &c);
    g2[gid] = cmk(c * scale, s * scale);
  }
  int fid = gid >> 11;
  int m = gid & (TN - 1);
  const float *W1, *B1, *W2, *B2;
  if (fid == 0){ W1=fw1; B1=fb1; W2=fw2; B2=fb2; }
  else if (fid == 1){ W1=gw1; B1=gb1; W2=gw2; B2=gb2; }
  else if (fid == 2){ W1=pw1; B1=pb1; W2=pw2; B2=pb2; }
  else { W1=qw1; B1=qb1; W2=qw2; B2=qb2; }
  int s = (fid == 0 || fid == 2) ? (TN - 1 - m) : m;
  double sv = (double)s;
  double z = (double)B2[0];
  #pragma unroll
  for (int h = 0; h < 5; h++)
    z += (double)W2[h] * tanh(sv * (double)W1[h] + (double)B1[h]);
  arr[fid * TN + m] = z * exp(-5.0 * sv);
}

// ---------- SO(3) helpers
__device__ __forceinline__ void mat_mul3(double* D, const double* A, const double* B){
  double r[9];
  #pragma unroll
  for (int i = 0; i < 3; i++)
    #pragma unroll
    for (int j = 0; j < 3; j++)
      r[i*3+j] = A[i*3]*B[j] + A[i*3+1]*B[3+j] + A[i*3+2]*B[6+j];
  #pragma unroll
  for (int k = 0; k < 9; k++) D[k] = r[k];
}
__device__ __forceinline__ void rod3(double* M, const double* a1, const double* a2,
                                     double z1, double z2){
  double G[9];
  #pragma unroll
  for (int k = 0; k < 9; k++) G[k] = a1[k]*z1 + a2[k]*z2;
  double wx = G[7], wy = G[2], wz = G[3];
  double th2 = wx*wx + wy*wy + wz*wz;
  double sa, cb;
  if (th2 < 1e-12){ sa = 1.0 - th2/6.0; cb = 0.5 - th2/24.0; }
  else { double th = sqrt(th2); sa = sin(th)/th; cb = (1.0 - cos(th))/th2; }
  double w[3] = {wx, wy, wz};
  #pragma unroll
  for (int i = 0; i < 3; i++)
    #pragma unroll
    for (int j = 0; j < 3; j++){
      double v = sa * G[i*3+j] + cb * (w[i]*w[j]);
      if (i == j) v += 1.0 - cb * th2;
      M[i*3+j] = v;
    }
}

// ---------- K2 merged: blocks 0-255 = H spectra (xQ folded), 256-319 = SO(3) scan, 320 = chat
__global__ __launch_bounds__(256) void k_front(
    const float* x, const float* A1f, const float* A2f,
    const double* arr, const cpx* Q, const cpx* tw,
    cpx* HsQ, double* Asc, cpx* chatp)
{
  __shared__ double smem[8192];   // 64 KB union
  int tid = threadIdx.x;
  int bid = blockIdx.x;
  if (bid < 256){
    cpx* part = (cpx*)smem;
    int f = bid >> 6;
    int jbase = (bid & 63) * 32;
    int chunk = tid & 7;
    int jl = tid >> 3;
    long long j = jbase + jl;
    long long jj = j + TN - 1;
    double s, c;
    sincos(-2.0 * PI_D * (double)jj / (double)LF, &s, &c);
    cpx W = cmk(c, s);
    long long m0 = (long long)chunk * 256;
    long long p0 = ((m0 + TN - 1) * jj) % LF;
    sincos(-2.0 * PI_D * (double)p0 / (double)LF, &s, &c);
    cpx ph = cmk(c, s);
    const double* a = arr + f * TN;
    cpx acc = cmk(0.0, 0.0);
    for (int m = (int)m0; m < (int)m0 + 256; m++){
      double av = a[m];
      acc.x += av * ph.x;
      acc.y += av * ph.y;
      ph = cmul(ph, W);
    }
    part[tid] = acc;
    __syncthreads();
    if (chunk == 0){
      cpx tot = cmk(0.0, 0.0);
      for (int q = 0; q < 8; q++) tot = cadd(tot, part[(jl << 3) + q]);
      HsQ[f * TN + (int)j] = cmul(tot, Q[j]);
    }
  } else if (bid < 320){
    int b = bid - 256;
    double (*S)[9] = (double(*)[9])smem;
    int k = tid;
    double a1[9], a2[9];
    #pragma unroll
    for (int i = 0; i < 3; i++)
      #pragma unroll
      for (int j = 0; j < 3; j++){
        a1[i*3+j] = (double)A1f[i*3+j] - (double)A1f[j*3+i];
        a2[i*3+j] = (double)A2f[i*3+j] - (double)A2f[j*3+i];
      }
    const float* xb = x + (size_t)b * TN * 2;
    double C[9] = {1,0,0, 0,1,0, 0,0,1};
    for (int i = 0; i < 8; i++){
      int t = k * 8 + i;
      if (t >= 1){
        double M[9];
        rod3(M, a1, a2, (double)xb[2*t], (double)xb[2*t+1]);
        mat_mul3(C, C, M);
      }
    }
    #pragma unroll
    for (int q = 0; q < 9; q++) S[k][q] = C[q];
    __syncthreads();
    for (int ofs = 1; ofs < 256; ofs <<= 1){
      double Lm[9], Rm[9];
      bool act = (k >= ofs);
      if (act){
        #pragma unroll
        for (int q = 0; q < 9; q++){ Lm[q] = S[k-ofs][q]; Rm[q] = S[k][q]; }
      }
      __syncthreads();
      if (act){
        double P[9];
        mat_mul3(P, Lm, Rm);
        #pragma unroll
        for (int q = 0; q < 9; q++) S[k][q] = P[q];
      }
      __syncthreads();
    }
    double P[9];
    if (k == 0){
      P[0]=1; P[1]=0; P[2]=0; P[3]=0; P[4]=1; P[5]=0; P[6]=0; P[7]=0; P[8]=1;
    } else {
      #pragma unroll
      for (int q = 0; q < 9; q++) P[q] = S[k-1][q];
    }
    for (int i = 0; i < 8; i++){
      int t = k * 8 + i;
      if (t >= 1){
        double M[9];
        rod3(M, a1, a2, (double)xb[2*t], (double)xb[2*t+1]);
        mat_mul3(P, P, M);
      }
      #pragma unroll
      for (int q = 0; q < 9; q++)
        Asc[(((size_t)b * 9 + q) << 11) + t] = P[q];
    }
  } else {
    // ---- chat: radix-8^4 DIF of chirp; stored permuted: chatp[(s&7)<<9 | s>>3]
    cpx* buf = (cpx*)smem;
    for (int m = tid; m < NF; m += 256){
      long long mm = (m <= 2048) ? m : (NF - m);
      long long qq = (mm * mm) % L2F;
      double s, c;
      sincos(-PI_D * (double)qq / (double)LF, &s, &c);
      buf[SW(m)] = cmk(c, s);
    }
    __syncthreads();
    r8_stage_fwd<9,512>(buf, tw); __syncthreads();
    r8_stage_fwd<6,512>(buf, tw); __syncthreads();
    r8_stage_fwd<3,512>(buf, tw); __syncthreads();
    r8_stage_fwd<0,512>(buf, tw); __syncthreads();
    for (int i = tid; i < NF; i += 256)
      chatp[((i & 7) << 9) | (i >> 3)] = buf[SW(i)];
  }
}

// ---------- K3: 2048-pt FFT, real-pair packed (2 channels per complex FFT),
// 256 threads, 32 KB LDS. Block = (b, p); p<4 -> channels (2p,2p+1), p=4 -> channel 8.
__global__ __launch_bounds__(256, 4) void k_fft_u(const double* Asc, const cpx* tw, cpx* U){
  __shared__ cpx buf[TN];
  int pos = threadIdx.x;                 // 0..255
  int b = blockIdx.x / 5, p = blockIdx.x % 5;
  int c0 = 2 * p;
  bool dual = (p < 4);
  const double* s0 = Asc + (((size_t)b * 9 + c0) << 11);
  const double* s1 = Asc + (((size_t)b * 9 + (dual ? c0 + 1 : c0)) << 11);
  const int R8[8] = {0,4,2,6,1,5,3,7};
  // C1: radix-8 stride 256, packed z = ch_a + i*ch_b staged directly from global
  {
    cpx a[8];
    #pragma unroll
    for (int j = 0; j < 8; j++){
      int idx = pos + (j << 8);
      a[j] = cmk(s0[idx], dual ? s1[idx] : 0.0);
    }
    fft8(a);
    #pragma unroll
    for (int q = 0; q < 8; q++){
      int k = R8[q]; cpx v = a[q];
      if (k) v = cmul(v, tw[(pos * k) << 1]);
      buf[SW(pos + (k << 8))] = v;
    }
  }
  __syncthreads();
  // wave-local: 8 segments of 256; wave w owns segments 2w, 2w+1
  int l = pos & 63;
  int ll = l & 31;
  int segb = ((((pos >> 6) << 1) + (l >> 5)) << 8);
  // CA: stride 32
  {
    int base = segb + ll;
    cpx a[8];
    #pragma unroll
    for (int j = 0; j < 8; j++) a[j] = buf[SW(base + (j << 5))];
    fft8(a);
    #pragma unroll
    for (int q = 0; q < 8; q++){
      int k = R8[q]; cpx v = a[q];
      if (k) v = cmul(v, tw[(ll * k) << 4]);
      buf[SW(base + (k << 5))] = v;
    }
  }
  wsync();
  // CB: stride 4
  {
    int base = segb + ((ll >> 2) << 5) + (ll & 3);
    cpx a[8];
    #pragma unroll
    for (int j = 0; j < 8; j++) a[j] = buf[SW(base + (j << 2))];
    fft8(a);
    #pragma unroll
    for (int q = 0; q < 8; q++){
      int k = R8[q]; cpx v = a[q];
      if (k) v = cmul(v, tw[((ll & 3) * k) << 7]);
      buf[SW(base + (k << 2))] = v;
    }
  }
  wsync();
  // CC: radix-4, stride 1 (2 groups per lane)
  {
    const int R4[4] = {0,2,1,3};
    #pragma unroll
    for (int h = 0; h < 2; h++){
      int base = segb + (((ll << 1) + h) << 2);
      cpx a4[4];
      #pragma unroll
      for (int j = 0; j < 4; j++) a4[j] = buf[SW(base + j)];
      fft4(a4);
      #pragma unroll
      for (int q = 0; q < 4; q++) buf[SW(base + R4[q])] = a4[q];
    }
  }
  __syncthreads();
  // unscramble + Hermitian unpack -> U rows c0, c0+1 (natural order, coalesced)
  cpx* dst0 = U + (((size_t)b * 9 + c0) << 11);
  cpx* dst1 = U + (((size_t)b * 9 + c0 + 1) << 11);
  #pragma unroll
  for (int ii = 0; ii < 8; ii++){
    int f = pos + (ii << 8);
    int s  = ((f & 7) << 8) + (((f >> 3) & 7) << 5) + (((f >> 6) & 7) << 2) + (f >> 9);
    int m  = (TN - f) & (TN - 1);
    int sm = ((m & 7) << 8) + (((m >> 3) & 7) << 5) + (((m >> 6) & 7) << 2) + (m >> 9);
    cpx Z = buf[SW(s)], Zm = buf[SW(sm)];
    dst0[f] = cmk(0.5 * (Z.x + Zm.x), 0.5 * (Z.y - Zm.y));          // (Z + conj(Zm))/2
    if (dual)
      dst1[f] = cmk(0.5 * (Z.y + Zm.y), 0.5 * (Zm.x - Z.x));        // (Z - conj(Zm))/(2i)
  }
}

// ---------- K4: CZT pair kernel, 256 threads, 2 butterfly groups per thread,
// e-invariant twiddles preloaded into registers, pruned invS1.
__global__ __launch_bounds__(256, 2) void k_czt(const cpx* U, const cpx* HsQ, const cpx* tw,
                                                const cpx* chatp, const cpx* g2, float* Rst){
  int gb = blockIdx.x;
  int pair = gb & 1;
  int bc = gb >> 1;
  int b = bc / 9, c = bc % 9;
  int ct = (c % 3) * 3 + (c / 3);        // inv(A) = A^T for SO(3)
  const cpx* Uc  = U + ((size_t)b * 9 + c)  * TN;
  const cpx* Uct = U + ((size_t)b * 9 + ct) * TN;
  __shared__ cpx buf[NF];
  int t = threadIdx.x;                   // 0..255
  int p0 = t, p1 = t + 256;              // S1/invS1 group indices
  int l = t & 63;
  int sb0 = ((t >> 6) << 1) << 9;        // wave's segment pair (each 512 cpx)
  int sb1 = sb0 + 512;
  int offA = l;                          // stride-64 stage offset within segment
  int offB = ((l >> 3) << 6) + (l & 7);  // stride-8 stage
  int offC = l << 3;                     // stride-1 stage
  int cp0 = (sb0 >> 3) + l;              // global group idx for chat (= seg*64 + l)
  int cp1 = cp0 + 64;
  int twA = l << 3;                      // W512^(l*k) = tw[twA*k]
  int twB = (l & 7) << 6;                // W64^((l&7)*k) = tw[twB*k]
  cpx pst0[4], pst1[4];
  const int R8[8] = {0,4,2,6,1,5,3,7};

  // preload e-invariant twiddle sets (reused by both groups and both passes)
  cpx twAr[7], twBr[7];
  #pragma unroll
  for (int k = 1; k < 8; k++){
    twAr[k-1] = tw[twA * k];
    twBr[k-1] = tw[twB * k];
  }

  #pragma unroll
  for (int e = 0; e < 2; e++){
    const cpx* Us = e ? Uc : Uct;
    const cpx* H = HsQ + (((pair << 1) | e) << 11);
    if (e) __syncthreads();              // buf free (prev pass invS1 done)
    cpx a[8], b8[8];
    // S1: staging fused, top half zero (radix-8, stride 512, cross-wave); groups p0,p1
    #pragma unroll
    for (int q = 0; q < 4; q++){
      a[q]  = cmul(Us[p0 + (q << 9)], H[p0 + (q << 9)]);
      b8[q] = cmul(Us[p1 + (q << 9)], H[p1 + (q << 9)]);
    }
    a[4] = a[0];
    a[5] = cmk(C8*(a[1].x + a[1].y), C8*(a[1].y - a[1].x));
    a[6] = cmk(a[2].y, -a[2].x);
    a[7] = cmk(C8*(a[3].y - a[3].x), -C8*(a[3].x + a[3].y));
    fft8_bc(a);
    b8[4] = b8[0];
    b8[5] = cmk(C8*(b8[1].x + b8[1].y), C8*(b8[1].y - b8[1].x));
    b8[6] = cmk(b8[2].y, -b8[2].x);
    b8[7] = cmk(C8*(b8[3].y - b8[3].x), -C8*(b8[3].x + b8[3].y));
    fft8_bc(b8);
    #pragma unroll
    for (int q = 0; q < 8; q++){
      int k = R8[q];
      cpx v = a[q], w = b8[q];
      if (k){ v = cmul(v, tw[p0 * k]); w = cmul(w, tw[p1 * k]); }
      buf[SW(p0 + (k << 9))] = v;
      buf[SW(p1 + (k << 9))] = w;
    }
    __syncthreads();
    // SA: stride 64 (wave-local, 2 segments interleaved)
    #pragma unroll
    for (int j = 0; j < 8; j++){
      a[j]  = buf[SW(sb0 + offA + (j << 6))];
      b8[j] = buf[SW(sb1 + offA + (j << 6))];
    }
    fft8(a); fft8(b8);
    #pragma unroll
    for (int q = 0; q < 8; q++){
      int k = R8[q];
      cpx v = a[q], w = b8[q];
      if (k){ cpx tk = twAr[k-1]; v = cmul(v, tk); w = cmul(w, tk); }
      buf[SW(sb0 + offA + (k << 6))] = v;
      buf[SW(sb1 + offA + (k << 6))] = w;
    }
    wsync();
    // SB: stride 8 (wave-local)
    #pragma unroll
    for (int j = 0; j < 8; j++){
      a[j]  = buf[SW(sb0 + offB + (j << 3))];
      b8[j] = buf[SW(sb1 + offB + (j << 3))];
    }
    fft8(a); fft8(b8);
    #pragma unroll
    for (int q = 0; q < 8; q++){
      int k = R8[q];
      cpx v = a[q], w = b8[q];
      if (k){ cpx tk = twBr[k-1]; v = cmul(v, tk); w = cmul(w, tk); }
      buf[SW(sb0 + offB + (k << 3))] = v;
      buf[SW(sb1 + offB + (k << 3))] = w;
    }
    wsync();
    // SC + chat + invSC fused in registers (stride 1)
    #pragma unroll
    for (int j = 0; j < 8; j++){
      a[j]  = buf[SW(sb0 + offC + j)];
      b8[j] = buf[SW(sb1 + offC + j)];
    }
    fft8(a); fft8(b8);
    #pragma unroll
    for (int q = 0; q < 8; q++){
      a[q]  = cmul(a[q],  chatp[(R8[q] << 9) | cp0]);
      b8[q] = cmul(b8[q], chatp[(R8[q] << 9) | cp1]);
    }
    ifft8(a); ifft8(b8);
    #pragma unroll
    for (int j = 0; j < 8; j++){
      buf[SW(sb0 + offC + j)] = a[j];
      buf[SW(sb1 + offC + j)] = b8[j];
    }
    wsync();
    // invSB (wave-local)
    #pragma unroll
    for (int q = 0; q < 8; q++){
      int k = R8[q];
      cpx v = buf[SW(sb0 + offB + (k << 3))];
      cpx w = buf[SW(sb1 + offB + (k << 3))];
      if (k){ cpx tk = twBr[k-1]; v = cmulc(v, tk); w = cmulc(w, tk); }
      a[q] = v; b8[q] = w;
    }
    ifft8(a); ifft8(b8);
    #pragma unroll
    for (int j = 0; j < 8; j++){
      buf[SW(sb0 + offB + (j << 3))] = a[j];
      buf[SW(sb1 + offB + (j << 3))] = b8[j];
    }
    wsync();
    // invSA (wave-local)
    #pragma unroll
    for (int q = 0; q < 8; q++){
      int k = R8[q];
      cpx v = buf[SW(sb0 + offA + (k << 6))];
      cpx w = buf[SW(sb1 + offA + (k << 6))];
      if (k){ cpx tk = twAr[k-1]; v = cmulc(v, tk); w = cmulc(w, tk); }
      a[q] = v; b8[q] = w;
    }
    ifft8(a); ifft8(b8);
    #pragma unroll
    for (int j = 0; j < 8; j++){
      buf[SW(sb0 + offA + (j << 6))] = a[j];
      buf[SW(sb1 + offA + (j << 6))] = b8[j];
    }
    __syncthreads();
    // invS1: outputs r = p + 512j; keep j<4 (r < 2048); pruned ifft8h
    #pragma unroll
    for (int q = 0; q < 8; q++){
      int k = R8[q];
      cpx v = buf[SW(p0 + (k << 9))];
      cpx w = buf[SW(p1 + (k << 9))];
      if (k){ v = cmulc(v, tw[p0 * k]); w = cmulc(w, tw[p1 * k]); }
      a[q] = v; b8[q] = w;
    }
    ifft8h(a); ifft8h(b8);
    if (e == 0){
      #pragma unroll
      for (int j = 0; j < 4; j++){ pst0[j] = a[j]; pst1[j] = b8[j]; }
    } else {
      size_t rb = ((size_t)(pair * (NB * 9) + bc) << 11);
      #pragma unroll
      for (int j = 0; j < 4; j++){
        int r0 = p0 + (j << 9), r1 = p1 + (j << 9);
        cpx pr0 = cmul(pst0[j], a[j]);
        cpx pr1 = cmul(pst1[j], b8[j]);
        cpx g0 = g2[r0], g1 = g2[r1];
        Rst[rb + r0] = (float)(pr0.x * g0.x - pr0.y * g0.y);
        Rst[rb + r1] = (float)(pr1.x * g1.x - pr1.y * g1.y);
      }
    }
  }
}

// ---------- K5: combine pair partials + transpose [b][c][r] -> out[b][r][c]
__global__ __launch_bounds__(256) void k_out(const float* Rst, float* out){
  __shared__ float ld[9][513];
  int b = blockIdx.x >> 2;
  int r0 = (blockIdx.x & 3) << 9;
  for (int idx = threadIdx.x; idx < 9 * 512; idx += 256){
    int cc = idx >> 9, r = idx & 511;
    size_t o0 = ((size_t)(b * 9 + cc) << 11) + r0 + r;
    ld[cc][r] = Rst[o0] + Rst[o0 + ((size_t)(NB * 9) << 11)];
  }
  __syncthreads();
  for (int idx = threadIdx.x; idx < 512 * 9; idx += 256){
    int r = idx / 9, cc = idx - 9 * r;
    out[((size_t)b * TN + r0 + r) * 9 + cc] = ld[cc][r];
  }
}

extern "C" void kernel_launch(void* const* d_in, const int* in_sizes, int n_in,
                              void* d_out, int out_size, void* d_ws, size_t ws_size,
                              hipStream_t stream){
  const float* x  = (const float*)d_in[0];
  const float* A1 = (const float*)d_in[1];
  const float* A2 = (const float*)d_in[2];
  const float* fpar[16];
  for (int i = 0; i < 16; i++) fpar[i] = (const float*)d_in[3 + i];
  float* out = (float*)d_out;

  // workspace carve (units: doubles), total ~28.7 MB
  double* ws = (double*)d_ws;
  size_t o = 0;
  double* arr  = ws + o;         o += 4 * TN;
  cpx* HsQ     = (cpx*)(ws + o); o += 2 * 4 * TN;
  cpx* tw      = (cpx*)(ws + o); o += 2 * NF;
  cpx* chatp   = (cpx*)(ws + o); o += 2 * NF;
  cpx* Q       = (cpx*)(ws + o); o += 2 * TN;
  cpx* g2      = (cpx*)(ws + o); o += 2 * TN;
  double* Asc  = ws + o;         o += (size_t)NB * TN * 9;      // 9.4 MB
  cpx* U       = (cpx*)(ws + o); o += 2 * (size_t)NB * 9 * TN;  // 18.9 MB
  float* Rst   = (float*)Asc;    // Asc dead after k_fft_u; 2*576*2048*4B = 9.4 MB exact fit

  k_prep<<<32, 256, 0, stream>>>(fpar[0], fpar[1], fpar[2], fpar[3],
                                 fpar[4], fpar[5], fpar[6], fpar[7],
                                 fpar[8], fpar[9], fpar[10], fpar[11],
                                 fpar[12], fpar[13], fpar[14], fpar[15],
                                 arr, tw, Q, g2);
  k_front<<<321, 256, 0, stream>>>(x, A1, A2, arr, Q, tw, HsQ, Asc, chatp);
  k_fft_u<<<NB * 5, 256, 0, stream>>>(Asc, tw, U);
  k_czt<<<NB * 9 * 2, 256, 0, stream>>>(U, HsQ, tw, chatp, g2, Rst);
  k_out<<<NB * 4, 256, 0, stream>>>(Rst, out);
}

// Round 9
// 235.811 us; speedup vs baseline: 1.1192x; 1.1192x over previous
//
#include <hip/hip_runtime.h>
#include <math.h>

#define TN 2048            // T
#define NF 4096            // Bluestein FFT length
#define NB 64              // batch
#define LF 6142LL          // L = 3T-2
#define L2F 12284LL        // 2L
#define PI_D 3.14159265358979323846264338327950288
#define C8 0.70710678118654752440084436210485

typedef double2 cpx;

__device__ __forceinline__ cpx cmk(double a, double b){ cpx r; r.x=a; r.y=b; return r; }
__device__ __forceinline__ cpx cadd(cpx a, cpx b){ return cmk(a.x+b.x, a.y+b.y); }
__device__ __forceinline__ cpx csub(cpx a, cpx b){ return cmk(a.x-b.x, a.y-b.y); }
__device__ __forceinline__ cpx cmul(cpx a, cpx b){ return cmk(a.x*b.x - a.y*b.y, a.x*b.y + a.y*b.x); }
__device__ __forceinline__ cpx cmulc(cpx a, cpx b){ return cmk(a.x*b.x + a.y*b.y, a.y*b.x - a.x*b.y); } // a*conj(b)

// LDS swizzle (cpx granularity, involution)
__device__ __forceinline__ int SW(int i){ return i ^ ((i >> 3) & 7); }

// wave-local sync: fences compiler + drains lgkmcnt; no cross-wave lock-step
__device__ __forceinline__ void wsync(){
  __builtin_amdgcn_wave_barrier();
  asm volatile("s_waitcnt lgkmcnt(0)" ::: "memory");
  __builtin_amdgcn_wave_barrier();
}

// ---------- 8-point register FFT (DIF, natural in; reg q holds freq R8[q]={0,4,2,6,1,5,3,7})
__device__ __forceinline__ void fft8_bc(cpx* a){
  cpx u, v, d;
  u=a[0]; v=a[2]; a[0]=cadd(u,v); a[2]=csub(u,v);
  u=a[1]; v=a[3]; a[1]=cadd(u,v); d=csub(u,v); a[3]=cmk(d.y, -d.x);
  u=a[4]; v=a[6]; a[4]=cadd(u,v); a[6]=csub(u,v);
  u=a[5]; v=a[7]; a[5]=cadd(u,v); d=csub(u,v); a[7]=cmk(d.y, -d.x);
  u=a[0]; v=a[1]; a[0]=cadd(u,v); a[1]=csub(u,v);
  u=a[2]; v=a[3]; a[2]=cadd(u,v); a[3]=csub(u,v);
  u=a[4]; v=a[5]; a[4]=cadd(u,v); a[5]=csub(u,v);
  u=a[6]; v=a[7]; a[6]=cadd(u,v); a[7]=csub(u,v);
}
__device__ __forceinline__ void fft8(cpx* a){
  cpx u, v, d;
  u=a[0]; v=a[4]; a[0]=cadd(u,v); a[4]=csub(u,v);
  u=a[1]; v=a[5]; a[1]=cadd(u,v); d=csub(u,v); a[5]=cmk(C8*(d.x+d.y), C8*(d.y-d.x));
  u=a[2]; v=a[6]; a[2]=cadd(u,v); d=csub(u,v); a[6]=cmk(d.y, -d.x);
  u=a[3]; v=a[7]; a[3]=cadd(u,v); d=csub(u,v); a[7]=cmk(C8*(d.y-d.x), -C8*(d.x+d.y));
  fft8_bc(a);
}
// unscaled inverse (input in fft8 reg order, output natural, x8)
__device__ __forceinline__ void ifft8(cpx* a){
  cpx u, v, t;
  u=a[0]; v=a[1]; a[0]=cadd(u,v); a[1]=csub(u,v);
  u=a[2]; v=a[3]; a[2]=cadd(u,v); a[3]=csub(u,v);
  u=a[4]; v=a[5]; a[4]=cadd(u,v); a[5]=csub(u,v);
  u=a[6]; v=a[7]; a[6]=cadd(u,v); a[7]=csub(u,v);
  u=a[0]; v=a[2]; a[0]=cadd(u,v); a[2]=csub(u,v);
  u=a[1]; t=a[3]; v=cmk(-t.y, t.x); a[1]=cadd(u,v); a[3]=csub(u,v);
  u=a[4]; v=a[6]; a[4]=cadd(u,v); a[6]=csub(u,v);
  u=a[5]; t=a[7]; v=cmk(-t.y, t.x); a[5]=cadd(u,v); a[7]=csub(u,v);
  u=a[0]; v=a[4]; a[0]=cadd(u,v); a[4]=csub(u,v);
  u=a[1]; t=a[5]; v=cmk(C8*(t.x-t.y), C8*(t.x+t.y)); a[1]=cadd(u,v); a[5]=csub(u,v);
  u=a[2]; t=a[6]; v=cmk(-t.y, t.x); a[2]=cadd(u,v); a[6]=csub(u,v);
  u=a[3]; t=a[7]; v=cmk(-C8*(t.x+t.y), C8*(t.x-t.y)); a[3]=cadd(u,v); a[7]=csub(u,v);
}
// pruned inverse: only outputs a[0..3] valid (skip the 4 csubs of the last level)
__device__ __forceinline__ void ifft8h(cpx* a){
  cpx u, v, t;
  u=a[0]; v=a[1]; a[0]=cadd(u,v); a[1]=csub(u,v);
  u=a[2]; v=a[3]; a[2]=cadd(u,v); a[3]=csub(u,v);
  u=a[4]; v=a[5]; a[4]=cadd(u,v); a[5]=csub(u,v);
  u=a[6]; v=a[7]; a[6]=cadd(u,v); a[7]=csub(u,v);
  u=a[0]; v=a[2]; a[0]=cadd(u,v); a[2]=csub(u,v);
  u=a[1]; t=a[3]; v=cmk(-t.y, t.x); a[1]=cadd(u,v); a[3]=csub(u,v);
  u=a[4]; v=a[6]; a[4]=cadd(u,v); a[6]=csub(u,v);
  u=a[5]; t=a[7]; v=cmk(-t.y, t.x); a[5]=cadd(u,v); a[7]=csub(u,v);
  u=a[0]; v=a[4]; a[0]=cadd(u,v);
  u=a[1]; t=a[5]; v=cmk(C8*(t.x-t.y), C8*(t.x+t.y)); a[1]=cadd(u,v);
  u=a[2]; t=a[6]; v=cmk(-t.y, t.x); a[2]=cadd(u,v);
  u=a[3]; t=a[7]; v=cmk(-C8*(t.x+t.y), C8*(t.x-t.y)); a[3]=cadd(u,v);
}
// 4-point DIF; reg q holds freq R4[q] = {0,2,1,3}
__device__ __forceinline__ void fft4(cpx* a){
  cpx u, v, d;
  u=a[0]; v=a[2]; a[0]=cadd(u,v); a[2]=csub(u,v);
  u=a[1]; v=a[3]; a[1]=cadd(u,v); d=csub(u,v); a[3]=cmk(d.y, -d.x);
  u=a[0]; v=a[1]; a[0]=cadd(u,v); a[1]=csub(u,v);
  u=a[2]; v=a[3]; a[2]=cadd(u,v); a[3]=csub(u,v);
}

// generic radix-8 DIF stage for 256-thread blocks (used by chat builder)
template<int LM, int NBF>
__device__ __forceinline__ void r8_stage_fwd(cpx* buf, const cpx* tw){
  const int R[8] = {0,4,2,6,1,5,3,7};
  for (int b = threadIdx.x; b < NBF; b += 256){
    int pos = b & ((1 << LM) - 1);
    int base = ((b >> LM) << (LM + 3)) | pos;
    cpx a[8];
    #pragma unroll
    for (int j = 0; j < 8; j++) a[j] = buf[SW(base + (j << LM))];
    fft8(a);
    #pragma unroll
    for (int q = 0; q < 8; q++){
      int k = R[q];
      cpx v = a[q];
      if (k) v = cmul(v, tw[(pos * k) << (9 - LM)]);
      buf[SW(base + (k << LM))] = v;
    }
  }
}

// ---------- K1: filters + tables
__global__ __launch_bounds__(256) void k_prep(
    const float* fw1, const float* fb1, const float* fw2, const float* fb2,
    const float* gw1, const float* gb1, const float* gw2, const float* gb2,
    const float* pw1, const float* pb1, const float* pw2, const float* pb2,
    const float* qw1, const float* qb1, const float* qw2, const float* qb2,
    double* arr, cpx* tw, cpx* Q, cpx* g2)
{
  int gid = blockIdx.x * 256 + threadIdx.x;   // < 8192
  if (gid < 4096){
    double s, c;
    sincos(-2.0 * PI_D * (double)gid / 4096.0, &s, &c);
    tw[gid] = cmk(c, s);
  }
  if (gid < 2048){
    long long i = gid;
    double s, c;
    long long a = ((2LL * TN - 2) * i) % LF;
    long long b = (i * i) % L2F;
    long long comb = (2 * a + b) % L2F;
    sincos(PI_D * (double)comb / (double)LF, &s, &c);
    Q[gid] = cmk(c, s);
    long long a2 = ((2LL * TN - 2 + i) * (TN - 1)) % LF;
    long long comb2 = (2 * a2 + b) % L2F;
    double phi = PI_D * (double)comb2 / (double)LF;
    double scale = 1.0 / ((double)LF * (double)LF) / (4096.0 * 4096.0);
    sincos(2.0 * phi, &s, &c);
    g2[gid] = cmk(c * scale, s * scale);
  }
  int fid = gid >> 11;
  int m = gid & (TN - 1);
  const float *W1, *B1, *W2, *B2;
  if (fid == 0){ W1=fw1; B1=fb1; W2=fw2; B2=fb2; }
  else if (fid == 1){ W1=gw1; B1=gb1; W2=gw2; B2=gb2; }
  else if (fid == 2){ W1=pw1; B1=pb1; W2=pw2; B2=pb2; }
  else { W1=qw1; B1=qb1; W2=qw2; B2=qb2; }
  int s = (fid == 0 || fid == 2) ? (TN - 1 - m) : m;
  double sv = (double)s;
  double z = (double)B2[0];
  #pragma unroll
  for (int h = 0; h < 5; h++)
    z += (double)W2[h] * tanh(sv * (double)W1[h] + (double)B1[h]);
  arr[fid * TN + m] = z * exp(-5.0 * sv);
}

// ---------- SO(3) helpers
__device__ __forceinline__ void mat_mul3(double* D, const double* A, const double* B){
  double r[9];
  #pragma unroll
  for (int i = 0; i < 3; i++)
    #pragma unroll
    for (int j = 0; j < 3; j++)
      r[i*3+j] = A[i*3]*B[j] + A[i*3+1]*B[3+j] + A[i*3+2]*B[6+j];
  #pragma unroll
  for (int k = 0; k < 9; k++) D[k] = r[k];
}
__device__ __forceinline__ void rod3(double* M, const double* a1, const double* a2,
                                     double z1, double z2){
  double G[9];
  #pragma unroll
  for (int k = 0; k < 9; k++) G[k] = a1[k]*z1 + a2[k]*z2;
  double wx = G[7], wy = G[2], wz = G[3];
  double th2 = wx*wx + wy*wy + wz*wz;
  double sa, cb;
  if (th2 < 1e-12){ sa = 1.0 - th2/6.0; cb = 0.5 - th2/24.0; }
  else { double th = sqrt(th2); sa = sin(th)/th; cb = (1.0 - cos(th))/th2; }
  double w[3] = {wx, wy, wz};
  #pragma unroll
  for (int i = 0; i < 3; i++)
    #pragma unroll
    for (int j = 0; j < 3; j++){
      double v = sa * G[i*3+j] + cb * (w[i]*w[j]);
      if (i == j) v += 1.0 - cb * th2;
      M[i*3+j] = v;
    }
}

// ---------- K2 merged: blocks 0-255 = H spectra (xQ folded), 256-319 = SO(3) scan, 320 = chat
__global__ __launch_bounds__(256) void k_front(
    const float* x, const float* A1f, const float* A2f,
    const double* arr, const cpx* Q, const cpx* tw,
    cpx* HsQ, double* Asc, cpx* chatp)
{
  __shared__ double smem[8192];   // 64 KB union
  int tid = threadIdx.x;
  int bid = blockIdx.x;
  if (bid < 256){
    cpx* part = (cpx*)smem;
    int f = bid >> 6;
    int jbase = (bid & 63) * 32;
    int chunk = tid & 7;
    int jl = tid >> 3;
    long long j = jbase + jl;
    long long jj = j + TN - 1;
    double s, c;
    sincos(-2.0 * PI_D * (double)jj / (double)LF, &s, &c);
    cpx W = cmk(c, s);
    long long m0 = (long long)chunk * 256;
    long long p0 = ((m0 + TN - 1) * jj) % LF;
    sincos(-2.0 * PI_D * (double)p0 / (double)LF, &s, &c);
    cpx ph = cmk(c, s);
    const double* a = arr + f * TN;
    cpx acc = cmk(0.0, 0.0);
    for (int m = (int)m0; m < (int)m0 + 256; m++){
      double av = a[m];
      acc.x += av * ph.x;
      acc.y += av * ph.y;
      ph = cmul(ph, W);
    }
    part[tid] = acc;
    __syncthreads();
    if (chunk == 0){
      cpx tot = cmk(0.0, 0.0);
      for (int q = 0; q < 8; q++) tot = cadd(tot, part[(jl << 3) + q]);
      HsQ[f * TN + (int)j] = cmul(tot, Q[j]);
    }
  } else if (bid < 320){
    int b = bid - 256;
    double (*S)[9] = (double(*)[9])smem;
    int k = tid;
    double a1[9], a2[9];
    #pragma unroll
    for (int i = 0; i < 3; i++)
      #pragma unroll
      for (int j = 0; j < 3; j++){
        a1[i*3+j] = (double)A1f[i*3+j] - (double)A1f[j*3+i];
        a2[i*3+j] = (double)A2f[i*3+j] - (double)A2f[j*3+i];
      }
    const float* xb = x + (size_t)b * TN * 2;
    double C[9] = {1,0,0, 0,1,0, 0,0,1};
    for (int i = 0; i < 8; i++){
      int t = k * 8 + i;
      if (t >= 1){
        double M[9];
        rod3(M, a1, a2, (double)xb[2*t], (double)xb[2*t+1]);
        mat_mul3(C, C, M);
      }
    }
    #pragma unroll
    for (int q = 0; q < 9; q++) S[k][q] = C[q];
    __syncthreads();
    for (int ofs = 1; ofs < 256; ofs <<= 1){
      double Lm[9], Rm[9];
      bool act = (k >= ofs);
      if (act){
        #pragma unroll
        for (int q = 0; q < 9; q++){ Lm[q] = S[k-ofs][q]; Rm[q] = S[k][q]; }
      }
      __syncthreads();
      if (act){
        double P[9];
        mat_mul3(P, Lm, Rm);
        #pragma unroll
        for (int q = 0; q < 9; q++) S[k][q] = P[q];
      }
      __syncthreads();
    }
    double P[9];
    if (k == 0){
      P[0]=1; P[1]=0; P[2]=0; P[3]=0; P[4]=1; P[5]=0; P[6]=0; P[7]=0; P[8]=1;
    } else {
      #pragma unroll
      for (int q = 0; q < 9; q++) P[q] = S[k-1][q];
    }
    for (int i = 0; i < 8; i++){
      int t = k * 8 + i;
      if (t >= 1){
        double M[9];
        rod3(M, a1, a2, (double)xb[2*t], (double)xb[2*t+1]);
        mat_mul3(P, P, M);
      }
      #pragma unroll
      for (int q = 0; q < 9; q++)
        Asc[(((size_t)b * 9 + q) << 11) + t] = P[q];
    }
  } else {
    // ---- chat: radix-8^4 DIF of chirp; stored permuted: chatp[(s&7)<<9 | s>>3]
    cpx* buf = (cpx*)smem;
    for (int m = tid; m < NF; m += 256){
      long long mm = (m <= 2048) ? m : (NF - m);
      long long qq = (mm * mm) % L2F;
      double s, c;
      sincos(-PI_D * (double)qq / (double)LF, &s, &c);
      buf[SW(m)] = cmk(c, s);
    }
    __syncthreads();
    r8_stage_fwd<9,512>(buf, tw); __syncthreads();
    r8_stage_fwd<6,512>(buf, tw); __syncthreads();
    r8_stage_fwd<3,512>(buf, tw); __syncthreads();
    r8_stage_fwd<0,512>(buf, tw); __syncthreads();
    for (int i = tid; i < NF; i += 256)
      chatp[((i & 7) << 9) | (i >> 3)] = buf[SW(i)];
  }
}

// ---------- K3: 2048-pt FFT, real-pair packed (2 channels per complex FFT),
// 256 threads, 32 KB LDS. Block = (b, p); p<4 -> channels (2p,2p+1), p=4 -> channel 8.
__global__ __launch_bounds__(256, 4) void k_fft_u(const double* Asc, const cpx* tw, cpx* U){
  __shared__ cpx buf[TN];
  int pos = threadIdx.x;                 // 0..255
  int b = blockIdx.x / 5, p = blockIdx.x % 5;
  int c0 = 2 * p;
  bool dual = (p < 4);
  const double* s0 = Asc + (((size_t)b * 9 + c0) << 11);
  const double* s1 = Asc + (((size_t)b * 9 + (dual ? c0 + 1 : c0)) << 11);
  const int R8[8] = {0,4,2,6,1,5,3,7};
  // C1: radix-8 stride 256, packed z = ch_a + i*ch_b staged directly from global
  {
    cpx a[8];
    #pragma unroll
    for (int j = 0; j < 8; j++){
      int idx = pos + (j << 8);
      a[j] = cmk(s0[idx], dual ? s1[idx] : 0.0);
    }
    fft8(a);
    #pragma unroll
    for (int q = 0; q < 8; q++){
      int k = R8[q]; cpx v = a[q];
      if (k) v = cmul(v, tw[(pos * k) << 1]);
      buf[SW(pos + (k << 8))] = v;
    }
  }
  __syncthreads();
  // wave-local: 8 segments of 256; wave w owns segments 2w, 2w+1
  int l = pos & 63;
  int ll = l & 31;
  int segb = ((((pos >> 6) << 1) + (l >> 5)) << 8);
  // CA: stride 32
  {
    int base = segb + ll;
    cpx a[8];
    #pragma unroll
    for (int j = 0; j < 8; j++) a[j] = buf[SW(base + (j << 5))];
    fft8(a);
    #pragma unroll
    for (int q = 0; q < 8; q++){
      int k = R8[q]; cpx v = a[q];
      if (k) v = cmul(v, tw[(ll * k) << 4]);
      buf[SW(base + (k << 5))] = v;
    }
  }
  wsync();
  // CB: stride 4
  {
    int base = segb + ((ll >> 2) << 5) + (ll & 3);
    cpx a[8];
    #pragma unroll
    for (int j = 0; j < 8; j++) a[j] = buf[SW(base + (j << 2))];
    fft8(a);
    #pragma unroll
    for (int q = 0; q < 8; q++){
      int k = R8[q]; cpx v = a[q];
      if (k) v = cmul(v, tw[((ll & 3) * k) << 7]);
      buf[SW(base + (k << 2))] = v;
    }
  }
  wsync();
  // CC: radix-4, stride 1 (2 groups per lane)
  {
    const int R4[4] = {0,2,1,3};
    #pragma unroll
    for (int h = 0; h < 2; h++){
      int base = segb + (((ll << 1) + h) << 2);
      cpx a4[4];
      #pragma unroll
      for (int j = 0; j < 4; j++) a4[j] = buf[SW(base + j)];
      fft4(a4);
      #pragma unroll
      for (int q = 0; q < 4; q++) buf[SW(base + R4[q])] = a4[q];
    }
  }
  __syncthreads();
  // unscramble + Hermitian unpack -> U rows c0, c0+1 (natural order, coalesced)
  cpx* dst0 = U + (((size_t)b * 9 + c0) << 11);
  cpx* dst1 = U + (((size_t)b * 9 + c0 + 1) << 11);
  #pragma unroll
  for (int ii = 0; ii < 8; ii++){
    int f = pos + (ii << 8);
    int s  = ((f & 7) << 8) + (((f >> 3) & 7) << 5) + (((f >> 6) & 7) << 2) + (f >> 9);
    int m  = (TN - f) & (TN - 1);
    int sm = ((m & 7) << 8) + (((m >> 3) & 7) << 5) + (((m >> 6) & 7) << 2) + (m >> 9);
    cpx Z = buf[SW(s)], Zm = buf[SW(sm)];
    dst0[f] = cmk(0.5 * (Z.x + Zm.x), 0.5 * (Z.y - Zm.y));          // (Z + conj(Zm))/2
    if (dual)
      dst1[f] = cmk(0.5 * (Z.y + Zm.y), 0.5 * (Zm.x - Z.x));        // (Z - conj(Zm))/(2i)
  }
}

// ---------- K4: CZT pair kernel, 256 threads, 2 butterfly groups per thread (ILP x2).
// Direct tw[] table loads (NO register preload — that spilled, R8), pruned invS1.
__global__ __launch_bounds__(256, 2) void k_czt(const cpx* U, const cpx* HsQ, const cpx* tw,
                                                const cpx* chatp, const cpx* g2, float* Rst){
  int gb = blockIdx.x;
  int pair = gb & 1;
  int bc = gb >> 1;
  int b = bc / 9, c = bc % 9;
  int ct = (c % 3) * 3 + (c / 3);        // inv(A) = A^T for SO(3)
  const cpx* Uc  = U + ((size_t)b * 9 + c)  * TN;
  const cpx* Uct = U + ((size_t)b * 9 + ct) * TN;
  __shared__ cpx buf[NF];
  int t = threadIdx.x;                   // 0..255
  int p0 = t, p1 = t + 256;              // S1/invS1 group indices
  int l = t & 63;
  int sb0 = ((t >> 6) << 1) << 9;        // wave's segment pair (each 512 cpx)
  int sb1 = sb0 + 512;
  int offA = l;                          // stride-64 stage offset within segment
  int offB = ((l >> 3) << 6) + (l & 7);  // stride-8 stage
  int offC = l << 3;                     // stride-1 stage
  int cp0 = (sb0 >> 3) + l;              // global group idx for chat (= seg*64 + l)
  int cp1 = cp0 + 64;
  int twA = l << 3;                      // W512^(l*k) = tw[twA*k]
  int twB = (l & 7) << 6;                // W64^((l&7)*k) = tw[twB*k]
  cpx pst0[4], pst1[4];
  const int R8[8] = {0,4,2,6,1,5,3,7};

  #pragma unroll
  for (int e = 0; e < 2; e++){
    const cpx* Us = e ? Uc : Uct;
    const cpx* H = HsQ + (((pair << 1) | e) << 11);
    if (e) __syncthreads();              // buf free (prev pass invS1 done)
    cpx a[8], b8[8];
    // S1: staging fused, top half zero (radix-8, stride 512, cross-wave); groups p0,p1
    #pragma unroll
    for (int q = 0; q < 4; q++){
      a[q]  = cmul(Us[p0 + (q << 9)], H[p0 + (q << 9)]);
      b8[q] = cmul(Us[p1 + (q << 9)], H[p1 + (q << 9)]);
    }
    a[4] = a[0];
    a[5] = cmk(C8*(a[1].x + a[1].y), C8*(a[1].y - a[1].x));
    a[6] = cmk(a[2].y, -a[2].x);
    a[7] = cmk(C8*(a[3].y - a[3].x), -C8*(a[3].x + a[3].y));
    fft8_bc(a);
    b8[4] = b8[0];
    b8[5] = cmk(C8*(b8[1].x + b8[1].y), C8*(b8[1].y - b8[1].x));
    b8[6] = cmk(b8[2].y, -b8[2].x);
    b8[7] = cmk(C8*(b8[3].y - b8[3].x), -C8*(b8[3].x + b8[3].y));
    fft8_bc(b8);
    #pragma unroll
    for (int q = 0; q < 8; q++){
      int k = R8[q];
      cpx v = a[q], w = b8[q];
      if (k){ v = cmul(v, tw[p0 * k]); w = cmul(w, tw[p1 * k]); }
      buf[SW(p0 + (k << 9))] = v;
      buf[SW(p1 + (k << 9))] = w;
    }
    __syncthreads();
    // SA: stride 64 (wave-local, 2 segments interleaved)
    #pragma unroll
    for (int j = 0; j < 8; j++){
      a[j]  = buf[SW(sb0 + offA + (j << 6))];
      b8[j] = buf[SW(sb1 + offA + (j << 6))];
    }
    fft8(a); fft8(b8);
    #pragma unroll
    for (int q = 0; q < 8; q++){
      int k = R8[q];
      cpx v = a[q], w = b8[q];
      if (k){ cpx tk = tw[twA * k]; v = cmul(v, tk); w = cmul(w, tk); }
      buf[SW(sb0 + offA + (k << 6))] = v;
      buf[SW(sb1 + offA + (k << 6))] = w;
    }
    wsync();
    // SB: stride 8 (wave-local)
    #pragma unroll
    for (int j = 0; j < 8; j++){
      a[j]  = buf[SW(sb0 + offB + (j << 3))];
      b8[j] = buf[SW(sb1 + offB + (j << 3))];
    }
    fft8(a); fft8(b8);
    #pragma unroll
    for (int q = 0; q < 8; q++){
      int k = R8[q];
      cpx v = a[q], w = b8[q];
      if (k){ cpx tk = tw[twB * k]; v = cmul(v, tk); w = cmul(w, tk); }
      buf[SW(sb0 + offB + (k << 3))] = v;
      buf[SW(sb1 + offB + (k << 3))] = w;
    }
    wsync();
    // SC + chat + invSC fused in registers (stride 1)
    #pragma unroll
    for (int j = 0; j < 8; j++){
      a[j]  = buf[SW(sb0 + offC + j)];
      b8[j] = buf[SW(sb1 + offC + j)];
    }
    fft8(a); fft8(b8);
    #pragma unroll
    for (int q = 0; q < 8; q++){
      a[q]  = cmul(a[q],  chatp[(R8[q] << 9) | cp0]);
      b8[q] = cmul(b8[q], chatp[(R8[q] << 9) | cp1]);
    }
    ifft8(a); ifft8(b8);
    #pragma unroll
    for (int j = 0; j < 8; j++){
      buf[SW(sb0 + offC + j)] = a[j];
      buf[SW(sb1 + offC + j)] = b8[j];
    }
    wsync();
    // invSB (wave-local)
    #pragma unroll
    for (int q = 0; q < 8; q++){
      int k = R8[q];
      cpx v = buf[SW(sb0 + offB + (k << 3))];
      cpx w = buf[SW(sb1 + offB + (k << 3))];
      if (k){ cpx tk = tw[twB * k]; v = cmulc(v, tk); w = cmulc(w, tk); }
      a[q] = v; b8[q] = w;
    }
    ifft8(a); ifft8(b8);
    #pragma unroll
    for (int j = 0; j < 8; j++){
      buf[SW(sb0 + offB + (j << 3))] = a[j];
      buf[SW(sb1 + offB + (j << 3))] = b8[j];
    }
    wsync();
    // invSA (wave-local)
    #pragma unroll
    for (int q = 0; q < 8; q++){
      int k = R8[q];
      cpx v = buf[SW(sb0 + offA + (k << 6))];
      cpx w = buf[SW(sb1 + offA + (k << 6))];
      if (k){ cpx tk = tw[twA * k]; v = cmulc(v, tk); w = cmulc(w, tk); }
      a[q] = v; b8[q] = w;
    }
    ifft8(a); ifft8(b8);
    #pragma unroll
    for (int j = 0; j < 8; j++){
      buf[SW(sb0 + offA + (j << 6))] = a[j];
      buf[SW(sb1 + offA + (j << 6))] = b8[j];
    }
    __syncthreads();
    // invS1: outputs r = p + 512j; keep j<4 (r < 2048); pruned ifft8h
    #pragma unroll
    for (int q = 0; q < 8; q++){
      int k = R8[q];
      cpx v = buf[SW(p0 + (k << 9))];
      cpx w = buf[SW(p1 + (k << 9))];
      if (k){ v = cmulc(v, tw[p0 * k]); w = cmulc(w, tw[p1 * k]); }
      a[q] = v; b8[q] = w;
    }
    ifft8h(a); ifft8h(b8);
    if (e == 0){
      #pragma unroll
      for (int j = 0; j < 4; j++){ pst0[j] = a[j]; pst1[j] = b8[j]; }
    } else {
      size_t rb = ((size_t)(pair * (NB * 9) + bc) << 11);
      #pragma unroll
      for (int j = 0; j < 4; j++){
        int r0 = p0 + (j << 9), r1 = p1 + (j << 9);
        cpx pr0 = cmul(pst0[j], a[j]);
        cpx pr1 = cmul(pst1[j], b8[j]);
        cpx g0 = g2[r0], g1 = g2[r1];
        Rst[rb + r0] = (float)(pr0.x * g0.x - pr0.y * g0.y);
        Rst[rb + r1] = (float)(pr1.x * g1.x - pr1.y * g1.y);
      }
    }
  }
}

// ---------- K5: combine pair partials + transpose [b][c][r] -> out[b][r][c]
__global__ __launch_bounds__(256) void k_out(const float* Rst, float* out){
  __shared__ float ld[9][513];
  int b = blockIdx.x >> 2;
  int r0 = (blockIdx.x & 3) << 9;
  for (int idx = threadIdx.x; idx < 9 * 512; idx += 256){
    int cc = idx >> 9, r = idx & 511;
    size_t o0 = ((size_t)(b * 9 + cc) << 11) + r0 + r;
    ld[cc][r] = Rst[o0] + Rst[o0 + ((size_t)(NB * 9) << 11)];
  }
  __syncthreads();
  for (int idx = threadIdx.x; idx < 512 * 9; idx += 256){
    int r = idx / 9, cc = idx - 9 * r;
    out[((size_t)b * TN + r0 + r) * 9 + cc] = ld[cc][r];
  }
}

extern "C" void kernel_launch(void* const* d_in, const int* in_sizes, int n_in,
                              void* d_out, int out_size, void* d_ws, size_t ws_size,
                              hipStream_t stream){
  const float* x  = (const float*)d_in[0];
  const float* A1 = (const float*)d_in[1];
  const float* A2 = (const float*)d_in[2];
  const float* fpar[16];
  for (int i = 0; i < 16; i++) fpar[i] = (const float*)d_in[3 + i];
  float* out = (float*)d_out;

  // workspace carve (units: doubles), total ~28.7 MB
  double* ws = (double*)d_ws;
  size_t o = 0;
  double* arr  = ws + o;         o += 4 * TN;
  cpx* HsQ     = (cpx*)(ws + o); o += 2 * 4 * TN;
  cpx* tw      = (cpx*)(ws + o); o += 2 * NF;
  cpx* chatp   = (cpx*)(ws + o); o += 2 * NF;
  cpx* Q       = (cpx*)(ws + o); o += 2 * TN;
  cpx* g2      = (cpx*)(ws + o); o += 2 * TN;
  double* Asc  = ws + o;         o += (size_t)NB * TN * 9;      // 9.4 MB
  cpx* U       = (cpx*)(ws + o); o += 2 * (size_t)NB * 9 * TN;  // 18.9 MB
  float* Rst   = (float*)Asc;    // Asc dead after k_fft_u; 2*576*2048*4B = 9.4 MB exact fit

  k_prep<<<32, 256, 0, stream>>>(fpar[0], fpar[1], fpar[2], fpar[3],
                                 fpar[4], fpar[5], fpar[6], fpar[7],
                                 fpar[8], fpar[9], fpar[10], fpar[11],
                                 fpar[12], fpar[13], fpar[14], fpar[15],
                                 arr, tw, Q, g2);
  k_front<<<321, 256, 0, stream>>>(x, A1, A2, arr, Q, tw, HsQ, Asc, chatp);
  k_fft_u<<<NB * 5, 256, 0, stream>>>(Asc, tw, U);
  k_czt<<<NB * 9 * 2, 256, 0, stream>>>(U, HsQ, tw, chatp, g2, Rst);
  k_out<<<NB * 4, 256, 0, stream>>>(Rst, out);
}